// Round 1
// baseline (30.254 us; speedup 1.0000x reference)
//
#include <hip/hip_runtime.h>

typedef __attribute__((ext_vector_type(4))) float  f32x4;
typedef __attribute__((ext_vector_type(8))) short  short8;
typedef __attribute__((ext_vector_type(2))) unsigned int u32x2;

#define BN_TOTAL 1600   // B*N = 8*200
#define NN 200          // N (neighbors)
#define EDIM 128
#define FDIM 16
#define AROW_STRIDE 40  // shorts per A-row in LDS (32 used + 8 pad for bank swizzle)

__device__ __forceinline__ unsigned short f2bf(float f) {
    unsigned u = __float_as_uint(f);
    u += 0x7FFFu + ((u >> 16) & 1u);   // round-to-nearest-even
    return (unsigned short)(u >> 16);
}

__device__ __forceinline__ float tanh_fast(float x) {
    // tanh(x) = 1 - 2/(1+e^{2x});  e^{2x} = exp2(x * 2*log2(e))
    float e = __builtin_amdgcn_exp2f(x * 2.8853900817779268f);
    float r = __builtin_amdgcn_rcpf(1.0f + e);
    return __builtin_fmaf(-2.0f, r, 1.0f);
}

// -------------------------------------------------------------------------
// Rowblock f32 GEMM: out[r][f] = sum_e in[r][e] * Wm[f][e] (+ bias[f])
// 8 rows per block, 256 threads = (f 0..127) x (c 0..1 e-halves).
// Used for hi = h @ W_node^T and out = agg @ W_out^T + b_out (in-place safe:
// all global reads of the rows happen before the barrier, writes after).
// -------------------------------------------------------------------------
__global__ __launch_bounds__(256) void rowproj_kernel(
    const float* __restrict__ in, const float* __restrict__ Wm,
    const float* __restrict__ bias, float* __restrict__ out, int has_bias)
{
    __shared__ float s[2048];  // 8KB: stage in rows [e][16(8 used)], reused for partials
    const int tid  = threadIdx.x;
    const int row0 = blockIdx.x * 8;

    for (int idx = tid; idx < 1024; idx += 256) {
        int r = idx >> 7, e = idx & 127;
        s[e * 16 + r] = in[(row0 + r) * EDIM + e];
    }
    __syncthreads();

    const int f = tid & 127;
    const int c = tid >> 7;
    float acc[8];
#pragma unroll
    for (int r = 0; r < 8; ++r) acc[r] = 0.0f;

    const float* wrow = Wm + f * EDIM + c * 64;
    for (int j = 0; j < 64; j += 4) {
        f32x4 w4 = *(const f32x4*)(wrow + j);
#pragma unroll
        for (int jj = 0; jj < 4; ++jj) {
            int e = c * 64 + j + jj;
            float w = w4[jj];
            f32x4 a = *(const f32x4*)(s + e * 16);
            f32x4 b = *(const f32x4*)(s + e * 16 + 4);
            acc[0] = __builtin_fmaf(a.x, w, acc[0]);
            acc[1] = __builtin_fmaf(a.y, w, acc[1]);
            acc[2] = __builtin_fmaf(a.z, w, acc[2]);
            acc[3] = __builtin_fmaf(a.w, w, acc[3]);
            acc[4] = __builtin_fmaf(b.x, w, acc[4]);
            acc[5] = __builtin_fmaf(b.y, w, acc[5]);
            acc[6] = __builtin_fmaf(b.z, w, acc[6]);
            acc[7] = __builtin_fmaf(b.w, w, acc[7]);
        }
    }
    __syncthreads();   // all LDS reads done before reuse
    {
        f32x4 lo = {acc[0], acc[1], acc[2], acc[3]};
        f32x4 hi = {acc[4], acc[5], acc[6], acc[7]};
        *(f32x4*)(s + (c * 128 + f) * 8)     = lo;
        *(f32x4*)(s + (c * 128 + f) * 8 + 4) = hi;
    }
    __syncthreads();
    if (tid < 128) {
        float bv = has_bias ? bias[tid] : 0.0f;
#pragma unroll
        for (int r = 0; r < 8; ++r) {
            float v = s[tid * 8 + r] + s[(128 + tid) * 8 + r] + bv;
            out[(row0 + r) * EDIM + tid] = v;
        }
    }
}

// -------------------------------------------------------------------------
// Fused message kernel: per (b,n) block computes
//   agg[e] = mean_m tanh( hi[e] + sum_f ef[m,f]*W_edge[e,f] + W[m]*W_weight[e] )
// via bf16 MFMA 16x16x32 with K = 32 (16 ef + 1 W + 15 zero pad).
// d_out holds hi on entry (read first, barrier-drained), agg on exit.
// -------------------------------------------------------------------------
__global__ __launch_bounds__(512) void msg_kernel(
    const float* __restrict__ ef, const float* __restrict__ Wadj,
    const float* __restrict__ W_edge, const float* __restrict__ W_weight,
    float* __restrict__ hi_agg)
{
    __shared__ short Abf[208 * AROW_STRIDE];   // 16640 B, bf16 A-tile [m][k]
    const int tid  = threadIdx.x;
    const int bn   = blockIdx.x;
    const int lane = tid & 63;
    const int wid  = tid >> 6;          // 8 waves = 8 e-tiles of 16
    const int g    = lane >> 4;         // k-group / row-group
    const int l15  = lane & 15;
    const int e_b  = wid * 16 + l15;    // this lane's e column

    // hi for this lane's output column (issued before barriers -> drained
    // by the compiler's vmcnt(0) at __syncthreads, so the late agg store
    // of other waves cannot race it)
    float hi_e = hi_agg[bn * EDIM + e_b];

    // B fragment (K=32 x N=16), built once, lives in VGPRs:
    // k<16: W_edge[e][k], k==16: W_weight[e], else 0
    short8 bfrag = {0, 0, 0, 0, 0, 0, 0, 0};
    if (g < 2) {
        const float* p = W_edge + e_b * FDIM + g * 8;
        f32x4 v0 = *(const f32x4*)(p);
        f32x4 v1 = *(const f32x4*)(p + 4);
        bfrag[0] = (short)f2bf(v0.x); bfrag[1] = (short)f2bf(v0.y);
        bfrag[2] = (short)f2bf(v0.z); bfrag[3] = (short)f2bf(v0.w);
        bfrag[4] = (short)f2bf(v1.x); bfrag[5] = (short)f2bf(v1.y);
        bfrag[6] = (short)f2bf(v1.z); bfrag[7] = (short)f2bf(v1.w);
    } else if (g == 2) {
        bfrag[0] = (short)f2bf(W_weight[e_b]);
    }

    // zero the A tile (pad cols 17..39 and pad rows 200..207 must be 0)
    {
        f32x4 z = {0.0f, 0.0f, 0.0f, 0.0f};
        for (int o = tid; o < 1040; o += 512)
            *(f32x4*)(Abf + o * 8) = z;
    }
    __syncthreads();

    // stage A: cols 0..15 = bf16(ef[m,:]), col 16 = bf16(W[m])
    for (int idx = tid; idx < 800; idx += 512) {      // 800 float4 = 200 rows x 16
        int m  = idx >> 2;
        int k4 = (idx & 3) * 4;
        f32x4 v = *(const f32x4*)(ef + (size_t)bn * (NN * FDIM) + idx * 4);
        unsigned lo = (unsigned)f2bf(v.x) | ((unsigned)f2bf(v.y) << 16);
        unsigned hi = (unsigned)f2bf(v.z) | ((unsigned)f2bf(v.w) << 16);
        u32x2 pk = {lo, hi};
        *(u32x2*)(Abf + m * AROW_STRIDE + k4) = pk;
    }
    for (int m = tid; m < NN; m += 512)
        Abf[m * AROW_STRIDE + 16] = (short)f2bf(Wadj[bn * NN + m]);
    __syncthreads();

    const f32x4 zero4 = {0.0f, 0.0f, 0.0f, 0.0f};
    float part = 0.0f;
#pragma unroll
    for (int mt = 0; mt < 13; ++mt) {
        short8 a = *(const short8*)(Abf + (mt * 16 + l15) * AROW_STRIDE + g * 8);
        f32x4 cacc = __builtin_amdgcn_mfma_f32_16x16x32_bf16(a, bfrag, zero4, 0, 0, 0);
        if (mt < 12) {
            part += tanh_fast(cacc[0] + hi_e);
            part += tanh_fast(cacc[1] + hi_e);
            part += tanh_fast(cacc[2] + hi_e);
            part += tanh_fast(cacc[3] + hi_e);
        } else if (g < 2) {   // rows 192..199 valid, 200..207 are pad
            part += tanh_fast(cacc[0] + hi_e);
            part += tanh_fast(cacc[1] + hi_e);
            part += tanh_fast(cacc[2] + hi_e);
            part += tanh_fast(cacc[3] + hi_e);
        }
    }
    // sum the 4 row-groups (lanes l, l^16, l^32, l^48 share column e)
    part += __shfl_xor(part, 16);
    part += __shfl_xor(part, 32);

    if (lane < 16)
        hi_agg[bn * EDIM + wid * 16 + lane] = part * (1.0f / 200.0f);
}

extern "C" void kernel_launch(void* const* d_in, const int* in_sizes, int n_in,
                              void* d_out, int out_size, void* d_ws, size_t ws_size,
                              hipStream_t stream) {
    const float* h        = (const float*)d_in[0];
    const float* ef       = (const float*)d_in[1];
    const float* W        = (const float*)d_in[2];
    const float* W_node   = (const float*)d_in[3];
    const float* W_edge   = (const float*)d_in[4];
    const float* W_weight = (const float*)d_in[5];
    const float* W_out    = (const float*)d_in[6];
    const float* b_out    = (const float*)d_in[7];
    float* out = (float*)d_out;

    // 1) d_out <- hi = h @ W_node^T
    rowproj_kernel<<<200, 256, 0, stream>>>(h, W_node, b_out, out, 0);
    // 2) d_out <- agg (fused edge proj + weight proj + tanh + mean)
    msg_kernel<<<BN_TOTAL, 512, 0, stream>>>(ef, W, W_edge, W_weight, out);
    // 3) d_out <- agg @ W_out^T + b_out (in-place)
    rowproj_kernel<<<200, 256, 0, stream>>>(out, W_out, b_out, out, 1);
}